// Round 4
// baseline (251.698 us; speedup 1.0000x reference)
//
#include <hip/hip_runtime.h>
#include <hip/hip_bf16.h>

#define B 2
#define S 2048
#define D 1024
#define NH 16
#define DH 64
#define M (B*S)
#define BQ 64
#define BK 64
#define KSCALE 0.18033688011112042f   // (1/sqrt(64)) * log2(e) — folded into Qb

typedef __hip_bfloat16 bf16;
typedef __attribute__((ext_vector_type(8))) short frag_ab;   // 8 bf16
typedef __attribute__((ext_vector_type(4))) float frag_cd;   // 4 f32
typedef unsigned long long ull;

// async global->LDS, 16B/lane; LDS dest = wave-uniform base + lane*16
__device__ __forceinline__ void gload_lds16(const bf16* g, bf16* l) {
    __builtin_amdgcn_global_load_lds((const __attribute__((address_space(1))) unsigned int*)g,
                                     (__attribute__((address_space(3))) unsigned int*)l,
                                     16, 0, 0);
}

// ---------- prep: z=0..3 -> weight convert+transpose T[n][k]=W[k][n]; z=4 -> x fp32->bf16
__global__ __launch_bounds__(256) void prep(const float* __restrict__ x,  bf16* __restrict__ xb,
                                            const float* __restrict__ W0, const float* __restrict__ W1,
                                            const float* __restrict__ W2, const float* __restrict__ W3,
                                            bf16* __restrict__ T0, bf16* __restrict__ T1,
                                            bf16* __restrict__ T2, bf16* __restrict__ T3) {
    if (blockIdx.z == 4) {
        const int l = blockIdx.y * 32 + blockIdx.x;
        int i = (l * 256 + threadIdx.x) * 4;
#pragma unroll
        for (int rep = 0; rep < 4; rep++, i += 1024 * 256 * 4) {
            const float4 v = *(const float4*)(x + i);
            __align__(8) bf16 t4[4] = {__float2bfloat16(v.x), __float2bfloat16(v.y),
                                       __float2bfloat16(v.z), __float2bfloat16(v.w)};
            *(ull*)(xb + i) = *(const ull*)t4;
        }
        return;
    }
    const float* src; bf16* dst;
    switch (blockIdx.z) {
        case 0: src = W0; dst = T0; break;
        case 1: src = W1; dst = T1; break;
        case 2: src = W2; dst = T2; break;
        default: src = W3; dst = T3; break;
    }
    __shared__ float t[32][33];
    const int tx = threadIdx.x & 31, ty = threadIdx.x >> 5;
    const int c0 = blockIdx.x * 32, r0 = blockIdx.y * 32;
#pragma unroll
    for (int i = 0; i < 4; i++)
        t[ty + 8 * i][tx] = src[(size_t)(r0 + ty + 8 * i) * D + c0 + tx];
    __syncthreads();
#pragma unroll
    for (int i = 0; i < 4; i++)
        dst[(size_t)(c0 + ty + 8 * i) * D + r0 + tx] = __float2bfloat16(t[tx][ty + 8 * i]);
}

// ---------- fused QKV GEMM: 128x128 tiles, 2-barrier K-loop, grid (24,32).
// Q third PRE-SCALED by KSCALE; K row-major; V third TRANSPOSED: Vt[bh][d][s].
__global__ __launch_bounds__(256) void gemm_qkv_all(const bf16* __restrict__ A, const bf16* __restrict__ Bt,
                                                    bf16* __restrict__ Qb, bf16* __restrict__ Kb,
                                                    bf16* __restrict__ Vt_g) {
    __shared__ __align__(16) bf16 As[128 * BK];
    __shared__ __align__(16) bf16 Bs[128 * BK];
    const int tid = threadIdx.x, wave = tid >> 6, lane = tid & 63;
    const int r16 = lane & 15, quad = lane >> 4;
    const int row0 = blockIdx.y * 128;
    const int col0 = blockIdx.x * 128;
    const int wm = (wave & 1) * 64, wn = (wave >> 1) * 64;

    frag_cd acc[4][4];
#pragma unroll
    for (int mt = 0; mt < 4; mt++)
#pragma unroll
        for (int nt = 0; nt < 4; nt++) acc[mt][nt] = frag_cd{0.f, 0.f, 0.f, 0.f};

    for (int k0 = 0; k0 < D; k0 += BK) {
        __syncthreads();
#pragma unroll
        for (int j = 0; j < 4; j++) {
            const int s = wave * 256 + j * 64 + lane;
            const int r = s >> 3;
            const int c = (s ^ r) & 7;
            gload_lds16(A  + (size_t)(row0 + r) * D + k0 + c * 8, &As[(wave * 256 + j * 64) * 8]);
            gload_lds16(Bt + (size_t)(col0 + r) * D + k0 + c * 8, &Bs[(wave * 256 + j * 64) * 8]);
        }
        __syncthreads();

        frag_ab af[4][2], bf[4][2];
#pragma unroll
        for (int mt = 0; mt < 4; mt++) {
            const int row = wm + mt * 16 + r16;
#pragma unroll
            for (int ks = 0; ks < 2; ks++)
                af[mt][ks] = *(const frag_ab*)&As[row * 64 + (((ks * 4 + quad) ^ (row & 7)) * 8)];
        }
#pragma unroll
        for (int nt = 0; nt < 4; nt++) {
            const int row = wn + nt * 16 + r16;
#pragma unroll
            for (int ks = 0; ks < 2; ks++)
                bf[nt][ks] = *(const frag_ab*)&Bs[row * 64 + (((ks * 4 + quad) ^ (row & 7)) * 8)];
        }
#pragma unroll
        for (int mt = 0; mt < 4; mt++)
#pragma unroll
            for (int nt = 0; nt < 4; nt++)
#pragma unroll
                for (int ks = 0; ks < 2; ks++)
                    acc[mt][nt] = __builtin_amdgcn_mfma_f32_16x16x32_bf16(
                        af[mt][ks], bf[nt][ks], acc[mt][nt], 0, 0, 0);
    }

    const int third = col0 >> 10;
    if (third < 2) {
        bf16* Out = (third == 0) ? Qb : Kb;
        const float sc = (third == 0) ? KSCALE : 1.f;
#pragma unroll
        for (int mt = 0; mt < 4; mt++)
#pragma unroll
            for (int nt = 0; nt < 4; nt++) {
                const int cl = (col0 + wn + nt * 16 + r16) & 1023;
#pragma unroll
                for (int rg = 0; rg < 4; rg++) {
                    const int row = row0 + wm + mt * 16 + quad * 4 + rg;
                    Out[(size_t)row * D + cl] = __float2bfloat16(acc[mt][nt][rg] * sc);
                }
            }
    } else {
        const int bb = row0 >> 11;
        const int sb0 = (row0 & 2047) + wm;
#pragma unroll
        for (int mt = 0; mt < 4; mt++)
#pragma unroll
            for (int nt = 0; nt < 4; nt++) {
                const int c  = (col0 + wn + nt * 16 + r16) - 2048;
                const int hh = c >> 6, dl = c & 63;
                const int sb = sb0 + mt * 16 + quad * 4;
                __align__(8) bf16 t4[4];
#pragma unroll
                for (int rg = 0; rg < 4; rg++) t4[rg] = __float2bfloat16(acc[mt][nt][rg]);
                *(ull*)(Vt_g + (((size_t)bb * 16 + hh) * 64 + dl) * S + sb) = *(const ull*)t4;
            }
    }
}

// ---------- Flash attention, S^T + transposed-O, BQ=64, static-max (R14)
// R15: NO LDS STAGING, NO BARRIERS. K/V are 256KB/head — L2-resident (learn_hip
// m169: staging L2-fit data is pure overhead). ka/vb/qf fragments load DIRECTLY
// from global (same per-lane addresses as the post-unswizzle LDS reads). The only
// LDS left is Ps (8KB, wave-private rows) for the P quad-exchange — so the entire
// kernel has zero __syncthreads: no vmcnt(0)+barrier drain per tile, waves
// free-run, loads schedule early, block's 4 waves share tiles via L1/L2.
__global__ __launch_bounds__(256) void attn_mfma(const bf16* __restrict__ Q,
                                                 const bf16* __restrict__ K,
                                                 const bf16* __restrict__ Vg,
                                                 bf16* __restrict__ Ctx) {
    __shared__ __align__(16) bf16 Ps[BQ * DH];   // [64][64] granule-XOR swizzled, rows wave-private

    const int tid = threadIdx.x, wave = tid >> 6, lane = tid & 63;
    const int r16 = lane & 15, quad = lane >> 4;
    const int bh = blockIdx.x, jy = blockIdx.y;
    const int qt = (jy < 16) ? jy : 47 - jy;   // per-CU balanced (sum=66 iters/CU)
    const int b = bh >> 4, h = bh & 15;
    const size_t base  = (size_t)b * S * D + (size_t)h * DH;
    const size_t vbase = (size_t)bh * DH * S;
    const int q0 = qt * BQ;
    const int qwave = q0 + wave * 16;
    const int nkt = qt + 1;

    // Q B-fragment direct from global (loop-invariant): Q[qwave+r16][ks*32+quad*8 ..+7]
    frag_ab qf[2];
    {
        const bf16* qp = Q + base + (size_t)(qwave + r16) * D + quad * 8;
#pragma unroll
        for (int ks = 0; ks < 2; ks++)
            qf[ks] = *(const frag_ab*)(qp + ks * 32);
    }

    // per-lane K/V fragment base pointers
    const bf16* kp = K  + base  + (size_t)r16 * D + quad * 8;   // + (k0+mk*16)*D + ks*32
    const bf16* vp = Vg + vbase + (size_t)r16 * S + quad * 8;   // + nd*16*S + k0 + ks*32

    // all-ones bf16 A-fragment for the l-sum MFMA (1.0 = 0x3F80)
    const frag_ab onesf = {(short)0x3F80, (short)0x3F80, (short)0x3F80, (short)0x3F80,
                           (short)0x3F80, (short)0x3F80, (short)0x3F80, (short)0x3F80};

    frag_cd Oacc[4];   // O^T tiles: row=d(quad*4+rg), col=q(r16)
#pragma unroll
    for (int nd = 0; nd < 4; nd++) Oacc[nd] = frag_cd{0.f, 0.f, 0.f, 0.f};
    frag_cd Lacc = frag_cd{0.f, 0.f, 0.f, 0.f};   // row-sum l: all 4 rg identical, col=r16

    for (int kt = 0; kt < nkt; kt++) {
        const int k0 = kt * BK;

        // ---- direct global fragment loads (independent; issue all, one vm-wait)
        frag_ab ka[4][2], vb[4][2];
#pragma unroll
        for (int mk = 0; mk < 4; mk++) {
            const bf16* kr = kp + (size_t)(k0 + mk * 16) * D;
#pragma unroll
            for (int ks = 0; ks < 2; ks++)
                ka[mk][ks] = *(const frag_ab*)(kr + ks * 32);
        }
#pragma unroll
        for (int nd = 0; nd < 4; nd++) {
            const bf16* vr = vp + (size_t)(nd * 16) * S + k0;
#pragma unroll
            for (int ks = 0; ks < 2; ks++)
                vb[nd][ks] = *(const frag_ab*)(vr + ks * 32);
        }

        // ---- QK^T: S^T C-layout col(r16)=q, row(quad*4+rg in mk-tile)=key
        frag_cd Sc[4];
#pragma unroll
        for (int mk = 0; mk < 4; mk++) {
            Sc[mk] = frag_cd{0.f, 0.f, 0.f, 0.f};
#pragma unroll
            for (int ks = 0; ks < 2; ks++)
                Sc[mk] = __builtin_amdgcn_mfma_f32_16x16x32_bf16(
                    ka[mk][ks], qf[ks], Sc[mk], 0, 0, 0);
        }

        // ---- static-max softmax: P = exp2(s) raw (log2-domain scores, KSCALE in Q)
        const bool domask = (k0 + BK - 1 > qwave);
        const int qg = qwave + r16;
        const int qrow = wave * 16 + r16;
#pragma unroll
        for (int mk = 0; mk < 4; mk++) {
            __align__(8) bf16 t4[4];
#pragma unroll
            for (int rg = 0; rg < 4; rg++) {
                float sv = Sc[mk][rg];
                if (domask) {
                    const int keyg = k0 + mk * 16 + quad * 4 + rg;
                    sv = (keyg <= qg) ? sv : -1e30f;
                }
                t4[rg] = __float2bfloat16(__builtin_amdgcn_exp2f(sv));
            }
            // packed P write: 4 consecutive keys/lane, granule-XOR swizzle (b64 floor)
            const int g2 = (mk * 4 + quad) ^ r16;
            *(ull*)&Ps[qrow * 64 + g2 * 4] = *(const ull*)t4;
        }

        // no barrier anywhere: Ps rows wave-private; per-wave LDS ops are in-order

        // ---- PV (transposed): O^T[d][q] += Vt(d rows) x P(q rows); l += ones x P
        frag_ab pa[2];
#pragma unroll
        for (int ks = 0; ks < 2; ks++) {
            const int gb = ks * 8 + quad * 2;
            union { ull u[2]; frag_ab f; } t;
            t.u[0] = *(const ull*)&Ps[qrow * 64 + ((gb    ) ^ r16) * 4];
            t.u[1] = *(const ull*)&Ps[qrow * 64 + ((gb + 1) ^ r16) * 4];
            pa[ks] = t.f;
        }
#pragma unroll
        for (int nd = 0; nd < 4; nd++)
#pragma unroll
            for (int ks = 0; ks < 2; ks++)
                Oacc[nd] = __builtin_amdgcn_mfma_f32_16x16x32_bf16(
                    vb[nd][ks], pa[ks], Oacc[nd], 0, 0, 0);
#pragma unroll
        for (int ks = 0; ks < 2; ks++)
            Lacc = __builtin_amdgcn_mfma_f32_16x16x32_bf16(
                onesf, pa[ks], Lacc, 0, 0, 0);
    }

    // epilogue: Ctx[q][d] = O^T[d][q] / l — lane holds 4 consecutive d -> packed b64
    // l for q=r16 is in Lacc (all 4 rg identical) — no cross-lane needed.
    {
        const float invl = 1.f / Lacc[0];
        const int qg = qwave + r16;
#pragma unroll
        for (int nd = 0; nd < 4; nd++) {
            __align__(8) bf16 t4[4];
#pragma unroll
            for (int rg = 0; rg < 4; rg++)
                t4[rg] = __float2bfloat16(Oacc[nd][rg] * invl);
            *(ull*)(Ctx + base + (size_t)qg * D + nd * 16 + quad * 4) = *(const ull*)t4;
        }
    }
}

// ---------- output projection, 64x128 tiles, single-barrier dbuf K-loop
__global__ __launch_bounds__(256) void gemm_out64(const bf16* __restrict__ A, const bf16* __restrict__ Bt,
                                                  const float* __restrict__ bias, float* __restrict__ Out) {
    __shared__ __align__(16) bf16 As[2][64 * BK];
    __shared__ __align__(16) bf16 Bs[2][128 * BK];
    const int tid = threadIdx.x, wave = tid >> 6, lane = tid & 63;
    const int r16 = lane & 15, quad = lane >> 4;
    const int row0 = blockIdx.y * 64;
    const int col0 = blockIdx.x * 128;
    const int wm = (wave & 1) * 32, wn = (wave >> 1) * 64;

    frag_cd acc[2][4];
#pragma unroll
    for (int mt = 0; mt < 2; mt++)
#pragma unroll
        for (int nt = 0; nt < 4; nt++) acc[mt][nt] = frag_cd{0.f, 0.f, 0.f, 0.f};

#pragma unroll
    for (int j = 0; j < 2; j++) {
        const int s = wave * 128 + j * 64 + lane;
        const int r = s >> 3, c = (s ^ r) & 7;
        gload_lds16(A + (size_t)(row0 + r) * D + c * 8, &As[0][(wave * 128 + j * 64) * 8]);
    }
#pragma unroll
    for (int j = 0; j < 4; j++) {
        const int s = wave * 256 + j * 64 + lane;
        const int r = s >> 3, c = (s ^ r) & 7;
        gload_lds16(Bt + (size_t)(col0 + r) * D + c * 8, &Bs[0][(wave * 256 + j * 64) * 8]);
    }
    __syncthreads();

    for (int kt = 0; kt < D / BK; kt++) {
        const int cur = kt & 1;
        if (kt + 1 < D / BK) {
            const int kn = (kt + 1) * BK;
#pragma unroll
            for (int j = 0; j < 2; j++) {
                const int s = wave * 128 + j * 64 + lane;
                const int r = s >> 3, c = (s ^ r) & 7;
                gload_lds16(A + (size_t)(row0 + r) * D + kn + c * 8,
                            &As[cur ^ 1][(wave * 128 + j * 64) * 8]);
            }
#pragma unroll
            for (int j = 0; j < 4; j++) {
                const int s = wave * 256 + j * 64 + lane;
                const int r = s >> 3, c = (s ^ r) & 7;
                gload_lds16(Bt + (size_t)(col0 + r) * D + kn + c * 8,
                            &Bs[cur ^ 1][(wave * 256 + j * 64) * 8]);
            }
        }

        frag_ab af[2][2], bf[4][2];
#pragma unroll
        for (int mt = 0; mt < 2; mt++) {
            const int row = wm + mt * 16 + r16;
#pragma unroll
            for (int ks = 0; ks < 2; ks++)
                af[mt][ks] = *(const frag_ab*)&As[cur][row * 64 + (((ks * 4 + quad) ^ (row & 7)) * 8)];
        }
#pragma unroll
        for (int nt = 0; nt < 4; nt++) {
            const int row = wn + nt * 16 + r16;
#pragma unroll
            for (int ks = 0; ks < 2; ks++)
                bf[nt][ks] = *(const frag_ab*)&Bs[cur][row * 64 + (((ks * 4 + quad) ^ (row & 7)) * 8)];
        }
#pragma unroll
        for (int mt = 0; mt < 2; mt++)
#pragma unroll
            for (int nt = 0; nt < 4; nt++)
#pragma unroll
                for (int ks = 0; ks < 2; ks++)
                    acc[mt][nt] = __builtin_amdgcn_mfma_f32_16x16x32_bf16(
                        af[mt][ks], bf[nt][ks], acc[mt][nt], 0, 0, 0);

        __syncthreads();
    }

#pragma unroll
    for (int mt = 0; mt < 2; mt++)
#pragma unroll
        for (int nt = 0; nt < 4; nt++) {
            const int col = col0 + wn + nt * 16 + r16;
            const float bv = bias[col];
#pragma unroll
            for (int rg = 0; rg < 4; rg++) {
                const int row = row0 + wm + mt * 16 + quad * 4 + rg;
                Out[(size_t)row * D + col] = acc[mt][nt][rg] + bv;
            }
        }
}

extern "C" void kernel_launch(void* const* d_in, const int* in_sizes, int n_in,
                              void* d_out, int out_size, void* d_ws, size_t ws_size,
                              hipStream_t stream) {
    const float* x  = (const float*)d_in[0];
    const float* Wq = (const float*)d_in[1];
    const float* Wk = (const float*)d_in[2];
    const float* Wv = (const float*)d_in[3];
    const float* Wo = (const float*)d_in[4];
    const float* bo = (const float*)d_in[5];
    float* out = (float*)d_out;

    bf16* xb    = (bf16*)d_ws;                 // [4096][1024]
    bf16* WqkvT = xb    + (size_t)M * D;       // [3072][1024] (WqT|WkT|WvT)
    bf16* WoT   = WqkvT + (size_t)3 * D * D;   // [1024][1024]
    bf16* Qb    = WoT   + (size_t)D * D;       // [B,S,D] (pre-scaled by KSCALE)
    bf16* Kb    = Qb    + (size_t)M * D;       // [B,S,D]
    bf16* Vt_g  = Kb    + (size_t)M * D;       // [32][64][2048]
    bf16* Ctxb  = Vt_g  + (size_t)M * D;       // [B,S,D]

    prep<<<dim3(32, 32, 5), 256, 0, stream>>>(x, xb, Wq, Wk, Wv, Wo,
                                              WqkvT, WqkvT + (size_t)D * D,
                                              WqkvT + (size_t)2 * D * D, WoT);
    gemm_qkv_all<<<dim3(24, 32), 256, 0, stream>>>(xb, WqkvT, Qb, Kb, Vt_g);
    attn_mfma<<<dim3(B * NH, S / BQ), 256, 0, stream>>>(Qb, Kb, Vt_g, Ctxb);
    gemm_out64<<<dim3(8, 64), 256, 0, stream>>>(Ctxb, WoT, bo, out);
}

// Round 6
// 179.250 us; speedup vs baseline: 1.4042x; 1.4042x over previous
//
#include <hip/hip_runtime.h>
#include <hip/hip_bf16.h>

#define B 2
#define S 2048
#define D 1024
#define NH 16
#define DH 64
#define M (B*S)
#define BQ 64
#define BK 64
#define KSCALE 0.18033688011112042f   // (1/sqrt(64)) * log2(e) — folded into Qb

typedef __hip_bfloat16 bf16;
typedef __attribute__((ext_vector_type(8))) short frag_ab;   // 8 bf16
typedef __attribute__((ext_vector_type(4))) float frag_cd;   // 4 f32
typedef unsigned long long ull;

// async global->LDS, 16B/lane; LDS dest = wave-uniform base + lane*16
__device__ __forceinline__ void gload_lds16(const bf16* g, bf16* l) {
    __builtin_amdgcn_global_load_lds((const __attribute__((address_space(1))) unsigned int*)g,
                                     (__attribute__((address_space(3))) unsigned int*)l,
                                     16, 0, 0);
}

// ---------- prep: z=0..3 -> weight convert+transpose T[n][k]=W[k][n]; z=4 -> x fp32->bf16
__global__ __launch_bounds__(256) void prep(const float* __restrict__ x,  bf16* __restrict__ xb,
                                            const float* __restrict__ W0, const float* __restrict__ W1,
                                            const float* __restrict__ W2, const float* __restrict__ W3,
                                            bf16* __restrict__ T0, bf16* __restrict__ T1,
                                            bf16* __restrict__ T2, bf16* __restrict__ T3) {
    if (blockIdx.z == 4) {
        const int l = blockIdx.y * 32 + blockIdx.x;
        int i = (l * 256 + threadIdx.x) * 4;
#pragma unroll
        for (int rep = 0; rep < 4; rep++, i += 1024 * 256 * 4) {
            const float4 v = *(const float4*)(x + i);
            __align__(8) bf16 t4[4] = {__float2bfloat16(v.x), __float2bfloat16(v.y),
                                       __float2bfloat16(v.z), __float2bfloat16(v.w)};
            *(ull*)(xb + i) = *(const ull*)t4;
        }
        return;
    }
    const float* src; bf16* dst;
    switch (blockIdx.z) {
        case 0: src = W0; dst = T0; break;
        case 1: src = W1; dst = T1; break;
        case 2: src = W2; dst = T2; break;
        default: src = W3; dst = T3; break;
    }
    __shared__ float t[32][33];
    const int tx = threadIdx.x & 31, ty = threadIdx.x >> 5;
    const int c0 = blockIdx.x * 32, r0 = blockIdx.y * 32;
#pragma unroll
    for (int i = 0; i < 4; i++)
        t[ty + 8 * i][tx] = src[(size_t)(r0 + ty + 8 * i) * D + c0 + tx];
    __syncthreads();
#pragma unroll
    for (int i = 0; i < 4; i++)
        dst[(size_t)(c0 + ty + 8 * i) * D + r0 + tx] = __float2bfloat16(t[tx][ty + 8 * i]);
}

// ---------- fused QKV GEMM: 128x128 tiles, 2-barrier K-loop, grid (24,32).
// Q third PRE-SCALED by KSCALE; K row-major; V third TRANSPOSED: Vt[bh][d][s].
__global__ __launch_bounds__(256) void gemm_qkv_all(const bf16* __restrict__ A, const bf16* __restrict__ Bt,
                                                    bf16* __restrict__ Qb, bf16* __restrict__ Kb,
                                                    bf16* __restrict__ Vt_g) {
    __shared__ __align__(16) bf16 As[128 * BK];
    __shared__ __align__(16) bf16 Bs[128 * BK];
    const int tid = threadIdx.x, wave = tid >> 6, lane = tid & 63;
    const int r16 = lane & 15, quad = lane >> 4;
    const int row0 = blockIdx.y * 128;
    const int col0 = blockIdx.x * 128;
    const int wm = (wave & 1) * 64, wn = (wave >> 1) * 64;

    frag_cd acc[4][4];
#pragma unroll
    for (int mt = 0; mt < 4; mt++)
#pragma unroll
        for (int nt = 0; nt < 4; nt++) acc[mt][nt] = frag_cd{0.f, 0.f, 0.f, 0.f};

    for (int k0 = 0; k0 < D; k0 += BK) {
        __syncthreads();
#pragma unroll
        for (int j = 0; j < 4; j++) {
            const int s = wave * 256 + j * 64 + lane;
            const int r = s >> 3;
            const int c = (s ^ r) & 7;
            gload_lds16(A  + (size_t)(row0 + r) * D + k0 + c * 8, &As[(wave * 256 + j * 64) * 8]);
            gload_lds16(Bt + (size_t)(col0 + r) * D + k0 + c * 8, &Bs[(wave * 256 + j * 64) * 8]);
        }
        __syncthreads();

        frag_ab af[4][2], bf[4][2];
#pragma unroll
        for (int mt = 0; mt < 4; mt++) {
            const int row = wm + mt * 16 + r16;
#pragma unroll
            for (int ks = 0; ks < 2; ks++)
                af[mt][ks] = *(const frag_ab*)&As[row * 64 + (((ks * 4 + quad) ^ (row & 7)) * 8)];
        }
#pragma unroll
        for (int nt = 0; nt < 4; nt++) {
            const int row = wn + nt * 16 + r16;
#pragma unroll
            for (int ks = 0; ks < 2; ks++)
                bf[nt][ks] = *(const frag_ab*)&Bs[row * 64 + (((ks * 4 + quad) ^ (row & 7)) * 8)];
        }
#pragma unroll
        for (int mt = 0; mt < 4; mt++)
#pragma unroll
            for (int nt = 0; nt < 4; nt++)
#pragma unroll
                for (int ks = 0; ks < 2; ks++)
                    acc[mt][nt] = __builtin_amdgcn_mfma_f32_16x16x32_bf16(
                        af[mt][ks], bf[nt][ks], acc[mt][nt], 0, 0, 0);
    }

    const int third = col0 >> 10;
    if (third < 2) {
        bf16* Out = (third == 0) ? Qb : Kb;
        const float sc = (third == 0) ? KSCALE : 1.f;
#pragma unroll
        for (int mt = 0; mt < 4; mt++)
#pragma unroll
            for (int nt = 0; nt < 4; nt++) {
                const int cl = (col0 + wn + nt * 16 + r16) & 1023;
#pragma unroll
                for (int rg = 0; rg < 4; rg++) {
                    const int row = row0 + wm + mt * 16 + quad * 4 + rg;
                    Out[(size_t)row * D + cl] = __float2bfloat16(acc[mt][nt][rg] * sc);
                }
            }
    } else {
        const int bb = row0 >> 11;
        const int sb0 = (row0 & 2047) + wm;
#pragma unroll
        for (int mt = 0; mt < 4; mt++)
#pragma unroll
            for (int nt = 0; nt < 4; nt++) {
                const int c  = (col0 + wn + nt * 16 + r16) - 2048;
                const int hh = c >> 6, dl = c & 63;
                const int sb = sb0 + mt * 16 + quad * 4;
                __align__(8) bf16 t4[4];
#pragma unroll
                for (int rg = 0; rg < 4; rg++) t4[rg] = __float2bfloat16(acc[mt][nt][rg]);
                *(ull*)(Vt_g + (((size_t)bb * 16 + hh) * 64 + dl) * S + sb) = *(const ull*)t4;
            }
    }
}

// ---------- Flash attention, R16 (resubmit): KEY-SPLIT waves + register-resident P.
// R14 structure (LDS-staged K/V, dbuf, 1 barrier/iter, static-max softmax) kept, but
// wave w owns keys [w*16,w*16+16) instead of 16 queries:
//  - ka: 2 b128 (own rows) instead of 8 (4x redundancy gone)
//  - QK^T computes ALL 64 q for those keys (qf[4 qb] hoisted from global, once)
//  - Sc C-layout (col=q=r16, row=key=quad*4+rg) IS the PV B-frag layout for
//    contraction over the wave's own keys -> P never touches LDS (Ps deleted)
//  - PV: 16x16x32 MFMA with upper 16 contraction slots zeroed in P-frag
//    (junk*0=0 on the V side); V reads 4 b64 (own key columns, swizzle-aware)
//  - l: VALU partial sums + end-of-kernel shuffle (no MFMA, no cross-lane in loop)
//  - epilogue: 3-barrier LDS tree reduction of the 4 per-wave partial O^T tiles
//    (reuses dead Ks/Vt space), wave 0 divides by l and stores.
// Per-wave-iter LDS: ~250 cyc -> ~50 cyc; VGPR ~140 -> launch_bounds(256,3).
__global__ __launch_bounds__(256, 3) void attn_mfma(const bf16* __restrict__ Q,
                                                    const bf16* __restrict__ K,
                                                    const bf16* __restrict__ Vg,
                                                    bf16* __restrict__ Ctx) {
    __shared__ __align__(16) bf16 Ks[2][BK * DH];   // 8 KB x2, rows=key, granule-XOR swizzle
    __shared__ __align__(16) bf16 Vt[2][BK * DH];   // 8 KB x2, rows=dim cols=key, same swizzle
    __shared__ float lred[4 * BQ];                  // per-wave l partials (1 KB)

    const int tid = threadIdx.x, wave = tid >> 6, lane = tid & 63;
    const int r16 = lane & 15, quad = lane >> 4;
    const int bh = blockIdx.x, jy = blockIdx.y;
    const int qt = (jy < 16) ? jy : 47 - jy;   // per-CU balanced (sum=66 iters/CU)
    const int b = bh >> 4, h = bh & 15;
    const size_t base  = (size_t)b * S * D + (size_t)h * DH;
    const size_t vbase = (size_t)bh * DH * S;
    const int q0 = qt * BQ;
    const int nkt = qt + 1;
    const int wkey = wave * 16;                // wave's key offset within each tile

    // ---- prologue: async-stage K/V tile 0 (buf 0)
#pragma unroll
    for (int j = 0; j < 2; j++) {
        const int s = wave * 128 + j * 64 + lane;
        const int r = s >> 3, c = (s ^ r) & 7;
        gload_lds16(K  + base  + (size_t)r * D + c * 8, &Ks[0][(wave * 128 + j * 64) * 8]);
        gload_lds16(Vg + vbase + (size_t)r * S + c * 8, &Vt[0][(wave * 128 + j * 64) * 8]);
    }

    // Q B-fragments for ALL 64 q rows, direct from global, once (loop-invariant)
    frag_ab qf[4][2];
#pragma unroll
    for (int qb = 0; qb < 4; qb++) {
        const bf16* qp = Q + base + (size_t)(q0 + qb * 16 + r16) * D + quad * 8;
#pragma unroll
        for (int ks = 0; ks < 2; ks++)
            qf[qb][ks] = *(const frag_ab*)(qp + ks * 32);
    }
    __syncthreads();   // K/V tile 0 resident

    frag_cd Oacc[4][4];   // [nd][qb] partial O^T over wave's keys: row=d(quad*4+rg), col=q(r16)
#pragma unroll
    for (int nd = 0; nd < 4; nd++)
#pragma unroll
        for (int qb = 0; qb < 4; qb++) Oacc[nd][qb] = frag_cd{0.f, 0.f, 0.f, 0.f};
    float lsum[4] = {0.f, 0.f, 0.f, 0.f};   // l partial per qb (lane's 4 keys)

    for (int kt = 0; kt < nkt; kt++) {
        const int k0  = kt * BK;
        const int cur = kt & 1;

        // ---- prefetch next K/V tile into alternate buffer (hidden under compute)
        if (kt + 1 < nkt) {
            const int kn = k0 + BK;
#pragma unroll
            for (int j = 0; j < 2; j++) {
                const int s = wave * 128 + j * 64 + lane;
                const int r = s >> 3, c = (s ^ r) & 7;
                gload_lds16(K  + base  + (size_t)(kn + r) * D + c * 8,
                            &Ks[cur ^ 1][(wave * 128 + j * 64) * 8]);
                gload_lds16(Vg + vbase + (size_t)r * S + kn + c * 8,
                            &Vt[cur ^ 1][(wave * 128 + j * 64) * 8]);
            }
        }

        // ---- ka: wave's own 16 key rows only (2 b128)
        const int krow = wkey + r16;
        frag_ab ka[2];
#pragma unroll
        for (int ks = 0; ks < 2; ks++)
            ka[ks] = *(const frag_ab*)&Ks[cur][krow * 64 + (((ks * 4 + quad) ^ (krow & 7)) * 8)];

        // ---- QK^T + static-max softmax, all 4 q-blocks; P packed into B-frags (regs)
        frag_ab pbf[4];
        const int keyg = k0 + wkey + quad * 4;   // lane's first key (global)
#pragma unroll
        for (int qb = 0; qb < 4; qb++) {
            frag_cd Sc = frag_cd{0.f, 0.f, 0.f, 0.f};
#pragma unroll
            for (int ks = 0; ks < 2; ks++)
                Sc = __builtin_amdgcn_mfma_f32_16x16x32_bf16(ka[ks], qf[qb][ks], Sc, 0, 0, 0);
            // col(r16)=q within qb, row(quad*4+rg)=key within wave's 16
            const bool msk = (k0 + wkey + 15) > (q0 + qb * 16);
            const int qg = q0 + qb * 16 + r16;
            float p[4];
#pragma unroll
            for (int rg = 0; rg < 4; rg++) {
                float sv = Sc[rg];
                if (msk) sv = (keyg + rg <= qg) ? sv : -1e30f;
                p[rg] = __builtin_amdgcn_exp2f(sv);
            }
            lsum[qb] += (p[0] + p[1]) + (p[2] + p[3]);
            __align__(8) bf16 t4[4] = {__float2bfloat16(p[0]), __float2bfloat16(p[1]),
                                       __float2bfloat16(p[2]), __float2bfloat16(p[3])};
            union { ull u[2]; frag_ab f; } tp;
            tp.u[0] = *(const ull*)t4;
            tp.u[1] = 0ull;               // zero upper contraction slots
            pbf[qb] = tp.f;
        }

        // ---- PV: Oacc[nd][qb] += Vt(own key cols) x P — contraction slots quad*8+e,
        // e<4 = wave keys quad*4+e (real), e>=4 = junk x 0 = 0.
#pragma unroll
        for (int nd = 0; nd < 4; nd++) {
            const int vrow = nd * 16 + r16;
            const int slot = ((wkey + quad * 4) >> 3) ^ (vrow & 7);
            union { ull u[2]; frag_ab f; } tv;
            tv.u[0] = *(const ull*)&Vt[cur][vrow * 64 + slot * 8 + (quad & 1) * 4];
            tv.u[1] = tv.u[0];            // junk half (multiplied by zero P)
#pragma unroll
            for (int qb = 0; qb < 4; qb++)
                Oacc[nd][qb] = __builtin_amdgcn_mfma_f32_16x16x32_bf16(
                    tv.f, pbf[qb], Oacc[nd][qb], 0, 0, 0);
        }

        __syncthreads();   // joins: prefetch complete + all waves done with cur bufs
    }

    // ---- epilogue: reduce 4 per-wave partial O^T + l, divide, store (wave 0)
    // intra-wave l: sum across quads (each quad held 4 of the wave's 16 keys)
#pragma unroll
    for (int qb = 0; qb < 4; qb++) {
        lsum[qb] += __shfl_xor(lsum[qb], 16, 64);
        lsum[qb] += __shfl_xor(lsum[qb], 32, 64);
    }
    if (quad == 0) {
#pragma unroll
        for (int qb = 0; qb < 4; qb++)
            lred[wave * 64 + qb * 16 + r16] = lsum[qb];
    }

    float* red0 = (float*)&Ks[0][0];   // 16 KB = 4096 f32 = full 64x64 O^T
    float* red1 = (float*)&Vt[0][0];
    // red layout [q][d], granule-XOR: idx = (qb*16+r16)*64 + ((nd*4+quad)^(r16&7))*4
    if (wave >= 2) {
        float* red = (wave == 2) ? red0 : red1;
#pragma unroll
        for (int nd = 0; nd < 4; nd++)
#pragma unroll
            for (int qb = 0; qb < 4; qb++) {
                const int idx = (qb * 16 + r16) * 64 + (((nd * 4 + quad) ^ (r16 & 7)) * 4);
                *(float4*)&red[idx] = float4{Oacc[nd][qb][0], Oacc[nd][qb][1],
                                             Oacc[nd][qb][2], Oacc[nd][qb][3]};
            }
    }
    __syncthreads();
    if (wave < 2) {
        float* red = (wave == 0) ? red0 : red1;
#pragma unroll
        for (int nd = 0; nd < 4; nd++)
#pragma unroll
            for (int qb = 0; qb < 4; qb++) {
                const int idx = (qb * 16 + r16) * 64 + (((nd * 4 + quad) ^ (r16 & 7)) * 4);
                const float4 v = *(const float4*)&red[idx];
#pragma unroll
                for (int rg = 0; rg < 4; rg++) Oacc[nd][qb][rg] += ((const float*)&v)[rg];
            }
    }
    __syncthreads();
    if (wave == 1) {
#pragma unroll
        for (int nd = 0; nd < 4; nd++)
#pragma unroll
            for (int qb = 0; qb < 4; qb++) {
                const int idx = (qb * 16 + r16) * 64 + (((nd * 4 + quad) ^ (r16 & 7)) * 4);
                *(float4*)&red0[idx] = float4{Oacc[nd][qb][0], Oacc[nd][qb][1],
                                              Oacc[nd][qb][2], Oacc[nd][qb][3]};
            }
    }
    __syncthreads();
    if (wave == 0) {
        float lt[4];
#pragma unroll
        for (int qb = 0; qb < 4; qb++) {
            const int qi = qb * 16 + r16;
            lt[qb] = 1.f / (lred[qi] + lred[64 + qi] + lred[128 + qi] + lred[192 + qi]);
        }
#pragma unroll
        for (int nd = 0; nd < 4; nd++)
#pragma unroll
            for (int qb = 0; qb < 4; qb++) {
                const int idx = (qb * 16 + r16) * 64 + (((nd * 4 + quad) ^ (r16 & 7)) * 4);
                const float4 v = *(const float4*)&red0[idx];
                __align__(8) bf16 t4[4];
#pragma unroll
                for (int rg = 0; rg < 4; rg++)
                    t4[rg] = __float2bfloat16((Oacc[nd][qb][rg] + ((const float*)&v)[rg]) * lt[qb]);
                *(ull*)(Ctx + base + (size_t)(q0 + qb * 16 + r16) * D + nd * 16 + quad * 4) =
                    *(const ull*)t4;
            }
    }
}

// ---------- output projection, 64x128 tiles, single-barrier dbuf K-loop
__global__ __launch_bounds__(256) void gemm_out64(const bf16* __restrict__ A, const bf16* __restrict__ Bt,
                                                  const float* __restrict__ bias, float* __restrict__ Out) {
    __shared__ __align__(16) bf16 As[2][64 * BK];
    __shared__ __align__(16) bf16 Bs[2][128 * BK];
    const int tid = threadIdx.x, wave = tid >> 6, lane = tid & 63;
    const int r16 = lane & 15, quad = lane >> 4;
    const int row0 = blockIdx.y * 64;
    const int col0 = blockIdx.x * 128;
    const int wm = (wave & 1) * 32, wn = (wave >> 1) * 64;

    frag_cd acc[2][4];
#pragma unroll
    for (int mt = 0; mt < 2; mt++)
#pragma unroll
        for (int nt = 0; nt < 4; nt++) acc[mt][nt] = frag_cd{0.f, 0.f, 0.f, 0.f};

#pragma unroll
    for (int j = 0; j < 2; j++) {
        const int s = wave * 128 + j * 64 + lane;
        const int r = s >> 3, c = (s ^ r) & 7;
        gload_lds16(A + (size_t)(row0 + r) * D + c * 8, &As[0][(wave * 128 + j * 64) * 8]);
    }
#pragma unroll
    for (int j = 0; j < 4; j++) {
        const int s = wave * 256 + j * 64 + lane;
        const int r = s >> 3, c = (s ^ r) & 7;
        gload_lds16(Bt + (size_t)(col0 + r) * D + c * 8, &Bs[0][(wave * 256 + j * 64) * 8]);
    }
    __syncthreads();

    for (int kt = 0; kt < D / BK; kt++) {
        const int cur = kt & 1;
        if (kt + 1 < D / BK) {
            const int kn = (kt + 1) * BK;
#pragma unroll
            for (int j = 0; j < 2; j++) {
                const int s = wave * 128 + j * 64 + lane;
                const int r = s >> 3, c = (s ^ r) & 7;
                gload_lds16(A + (size_t)(row0 + r) * D + kn + c * 8,
                            &As[cur ^ 1][(wave * 128 + j * 64) * 8]);
            }
#pragma unroll
            for (int j = 0; j < 4; j++) {
                const int s = wave * 256 + j * 64 + lane;
                const int r = s >> 3, c = (s ^ r) & 7;
                gload_lds16(Bt + (size_t)(col0 + r) * D + kn + c * 8,
                            &Bs[cur ^ 1][(wave * 256 + j * 64) * 8]);
            }
        }

        frag_ab af[2][2], bf[4][2];
#pragma unroll
        for (int mt = 0; mt < 2; mt++) {
            const int row = wm + mt * 16 + r16;
#pragma unroll
            for (int ks = 0; ks < 2; ks++)
                af[mt][ks] = *(const frag_ab*)&As[cur][row * 64 + (((ks * 4 + quad) ^ (row & 7)) * 8)];
        }
#pragma unroll
        for (int nt = 0; nt < 4; nt++) {
            const int row = wn + nt * 16 + r16;
#pragma unroll
            for (int ks = 0; ks < 2; ks++)
                bf[nt][ks] = *(const frag_ab*)&Bs[cur][row * 64 + (((ks * 4 + quad) ^ (row & 7)) * 8)];
        }
#pragma unroll
        for (int mt = 0; mt < 2; mt++)
#pragma unroll
            for (int nt = 0; nt < 4; nt++)
#pragma unroll
                for (int ks = 0; ks < 2; ks++)
                    acc[mt][nt] = __builtin_amdgcn_mfma_f32_16x16x32_bf16(
                        af[mt][ks], bf[nt][ks], acc[mt][nt], 0, 0, 0);

        __syncthreads();
    }

#pragma unroll
    for (int mt = 0; mt < 2; mt++)
#pragma unroll
        for (int nt = 0; nt < 4; nt++) {
            const int col = col0 + wn + nt * 16 + r16;
            const float bv = bias[col];
#pragma unroll
            for (int rg = 0; rg < 4; rg++) {
                const int row = row0 + wm + mt * 16 + quad * 4 + rg;
                Out[(size_t)row * D + col] = acc[mt][nt][rg] + bv;
            }
        }
}

extern "C" void kernel_launch(void* const* d_in, const int* in_sizes, int n_in,
                              void* d_out, int out_size, void* d_ws, size_t ws_size,
                              hipStream_t stream) {
    const float* x  = (const float*)d_in[0];
    const float* Wq = (const float*)d_in[1];
    const float* Wk = (const float*)d_in[2];
    const float* Wv = (const float*)d_in[3];
    const float* Wo = (const float*)d_in[4];
    const float* bo = (const float*)d_in[5];
    float* out = (float*)d_out;

    bf16* xb    = (bf16*)d_ws;                 // [4096][1024]
    bf16* WqkvT = xb    + (size_t)M * D;       // [3072][1024] (WqT|WkT|WvT)
    bf16* WoT   = WqkvT + (size_t)3 * D * D;   // [1024][1024]
    bf16* Qb    = WoT   + (size_t)D * D;       // [B,S,D] (pre-scaled by KSCALE)
    bf16* Kb    = Qb    + (size_t)M * D;       // [B,S,D]
    bf16* Vt_g  = Kb    + (size_t)M * D;       // [32][64][2048]
    bf16* Ctxb  = Vt_g  + (size_t)M * D;       // [B,S,D]

    prep<<<dim3(32, 32, 5), 256, 0, stream>>>(x, xb, Wq, Wk, Wv, Wo,
                                              WqkvT, WqkvT + (size_t)D * D,
                                              WqkvT + (size_t)2 * D * D, WoT);
    gemm_qkv_all<<<dim3(24, 32), 256, 0, stream>>>(xb, WqkvT, Qb, Kb, Vt_g);
    attn_mfma<<<dim3(B * NH, S / BQ), 256, 0, stream>>>(Qb, Kb, Vt_g, Ctxb);
    gemm_out64<<<dim3(8, 64), 256, 0, stream>>>(Ctxb, WoT, bo, out);
}

// Round 7
// 177.537 us; speedup vs baseline: 1.4177x; 1.0097x over previous
//
#include <hip/hip_runtime.h>
#include <hip/hip_bf16.h>

#define B 2
#define S 2048
#define D 1024
#define NH 16
#define DH 64
#define M (B*S)
#define BQ 64
#define BK 64
#define KSCALE 0.18033688011112042f   // (1/sqrt(64)) * log2(e) — folded into Qb

typedef __hip_bfloat16 bf16;
typedef __attribute__((ext_vector_type(8))) short frag_ab;   // 8 bf16
typedef __attribute__((ext_vector_type(4))) float frag_cd;   // 4 f32
typedef unsigned long long ull;

// async global->LDS, 16B/lane; LDS dest = wave-uniform base + lane*16
__device__ __forceinline__ void gload_lds16(const bf16* g, bf16* l) {
    __builtin_amdgcn_global_load_lds((const __attribute__((address_space(1))) unsigned int*)g,
                                     (__attribute__((address_space(3))) unsigned int*)l,
                                     16, 0, 0);
}

// ---------- prep: z=0..3 -> weight convert+transpose T[n][k]=W[k][n]; z=4 -> x fp32->bf16
__global__ __launch_bounds__(256) void prep(const float* __restrict__ x,  bf16* __restrict__ xb,
                                            const float* __restrict__ W0, const float* __restrict__ W1,
                                            const float* __restrict__ W2, const float* __restrict__ W3,
                                            bf16* __restrict__ T0, bf16* __restrict__ T1,
                                            bf16* __restrict__ T2, bf16* __restrict__ T3) {
    if (blockIdx.z == 4) {
        const int l = blockIdx.y * 32 + blockIdx.x;
        int i = (l * 256 + threadIdx.x) * 4;
#pragma unroll
        for (int rep = 0; rep < 4; rep++, i += 1024 * 256 * 4) {
            const float4 v = *(const float4*)(x + i);
            __align__(8) bf16 t4[4] = {__float2bfloat16(v.x), __float2bfloat16(v.y),
                                       __float2bfloat16(v.z), __float2bfloat16(v.w)};
            *(ull*)(xb + i) = *(const ull*)t4;
        }
        return;
    }
    const float* src; bf16* dst;
    switch (blockIdx.z) {
        case 0: src = W0; dst = T0; break;
        case 1: src = W1; dst = T1; break;
        case 2: src = W2; dst = T2; break;
        default: src = W3; dst = T3; break;
    }
    __shared__ float t[32][33];
    const int tx = threadIdx.x & 31, ty = threadIdx.x >> 5;
    const int c0 = blockIdx.x * 32, r0 = blockIdx.y * 32;
#pragma unroll
    for (int i = 0; i < 4; i++)
        t[ty + 8 * i][tx] = src[(size_t)(r0 + ty + 8 * i) * D + c0 + tx];
    __syncthreads();
#pragma unroll
    for (int i = 0; i < 4; i++)
        dst[(size_t)(c0 + ty + 8 * i) * D + r0 + tx] = __float2bfloat16(t[tx][ty + 8 * i]);
}

// ---------- fused QKV GEMM: 128x128 tiles, 2-barrier K-loop, grid (24,32).
// Q third PRE-SCALED by KSCALE; K row-major; V third TRANSPOSED: Vt[bh][d][s].
__global__ __launch_bounds__(256) void gemm_qkv_all(const bf16* __restrict__ A, const bf16* __restrict__ Bt,
                                                    bf16* __restrict__ Qb, bf16* __restrict__ Kb,
                                                    bf16* __restrict__ Vt_g) {
    __shared__ __align__(16) bf16 As[128 * BK];
    __shared__ __align__(16) bf16 Bs[128 * BK];
    const int tid = threadIdx.x, wave = tid >> 6, lane = tid & 63;
    const int r16 = lane & 15, quad = lane >> 4;
    const int row0 = blockIdx.y * 128;
    const int col0 = blockIdx.x * 128;
    const int wm = (wave & 1) * 64, wn = (wave >> 1) * 64;

    frag_cd acc[4][4];
#pragma unroll
    for (int mt = 0; mt < 4; mt++)
#pragma unroll
        for (int nt = 0; nt < 4; nt++) acc[mt][nt] = frag_cd{0.f, 0.f, 0.f, 0.f};

    for (int k0 = 0; k0 < D; k0 += BK) {
        __syncthreads();
#pragma unroll
        for (int j = 0; j < 4; j++) {
            const int s = wave * 256 + j * 64 + lane;
            const int r = s >> 3;
            const int c = (s ^ r) & 7;
            gload_lds16(A  + (size_t)(row0 + r) * D + k0 + c * 8, &As[(wave * 256 + j * 64) * 8]);
            gload_lds16(Bt + (size_t)(col0 + r) * D + k0 + c * 8, &Bs[(wave * 256 + j * 64) * 8]);
        }
        __syncthreads();

        frag_ab af[4][2], bf[4][2];
#pragma unroll
        for (int mt = 0; mt < 4; mt++) {
            const int row = wm + mt * 16 + r16;
#pragma unroll
            for (int ks = 0; ks < 2; ks++)
                af[mt][ks] = *(const frag_ab*)&As[row * 64 + (((ks * 4 + quad) ^ (row & 7)) * 8)];
        }
#pragma unroll
        for (int nt = 0; nt < 4; nt++) {
            const int row = wn + nt * 16 + r16;
#pragma unroll
            for (int ks = 0; ks < 2; ks++)
                bf[nt][ks] = *(const frag_ab*)&Bs[row * 64 + (((ks * 4 + quad) ^ (row & 7)) * 8)];
        }
#pragma unroll
        for (int mt = 0; mt < 4; mt++)
#pragma unroll
            for (int nt = 0; nt < 4; nt++)
#pragma unroll
                for (int ks = 0; ks < 2; ks++)
                    acc[mt][nt] = __builtin_amdgcn_mfma_f32_16x16x32_bf16(
                        af[mt][ks], bf[nt][ks], acc[mt][nt], 0, 0, 0);
    }

    const int third = col0 >> 10;
    if (third < 2) {
        bf16* Out = (third == 0) ? Qb : Kb;
        const float sc = (third == 0) ? KSCALE : 1.f;
#pragma unroll
        for (int mt = 0; mt < 4; mt++)
#pragma unroll
            for (int nt = 0; nt < 4; nt++) {
                const int cl = (col0 + wn + nt * 16 + r16) & 1023;
#pragma unroll
                for (int rg = 0; rg < 4; rg++) {
                    const int row = row0 + wm + mt * 16 + quad * 4 + rg;
                    Out[(size_t)row * D + cl] = __float2bfloat16(acc[mt][nt][rg] * sc);
                }
            }
    } else {
        const int bb = row0 >> 11;
        const int sb0 = (row0 & 2047) + wm;
#pragma unroll
        for (int mt = 0; mt < 4; mt++)
#pragma unroll
            for (int nt = 0; nt < 4; nt++) {
                const int c  = (col0 + wn + nt * 16 + r16) - 2048;
                const int hh = c >> 6, dl = c & 63;
                const int sb = sb0 + mt * 16 + quad * 4;
                __align__(8) bf16 t4[4];
#pragma unroll
                for (int rg = 0; rg < 4; rg++) t4[rg] = __float2bfloat16(acc[mt][nt][rg]);
                *(ull*)(Vt_g + (((size_t)bb * 16 + hh) * 64 + dl) * S + sb) = *(const ull*)t4;
            }
    }
}

// ---------- Flash attention R17: R14 body + PAIRED q-tiles + BK=128 chunks.
// Block (bh, jy) handles q-tiles qtA=pj (short) and qtB=31-pj (long); pj = jy<8 ?
// jy : 23-jy balances every CU's 2-block chunk total at exactly 25. The short
// tile's K-range is a prefix of the long one's, so ONE pass over K/V serves both
// (staging events 66->49 per CU). Each chunk stages 128 keys as two 64-key halves
// (events 49->25); per-half body = R14 verbatim vs Ks[buf][half]/Vt[buf][half].
// ka/vb hoisted, shared by both tiles. Static-max softmax (R14), P via Ps (8KB,
// wave-private rows), l via ones-MFMA. LDS 72KB -> 2 blocks/CU (8 waves const).
__global__ __launch_bounds__(256, 2) void attn_mfma(const bf16* __restrict__ Q,
                                                    const bf16* __restrict__ K,
                                                    const bf16* __restrict__ Vg,
                                                    bf16* __restrict__ Ctx) {
    __shared__ __align__(16) bf16 Ks[2][2][BK * DH];   // [buf][half][64key x 64d] 16KB/buf
    __shared__ __align__(16) bf16 Vt[2][2][BK * DH];   // [buf][half][64d x 64key] 16KB/buf
    __shared__ __align__(16) bf16 Ps[BQ * DH];         // 8KB, granule-XOR, rows wave-private

    const int tid = threadIdx.x, wave = tid >> 6, lane = tid & 63;
    const int r16 = lane & 15, quad = lane >> 4;
    const int bh = blockIdx.x, jy = blockIdx.y;
    const int pj = (jy < 8) ? jy : 23 - jy;    // CU-balanced pairing (2 blocks sum 25 chunks)
    const int b = bh >> 4, h = bh & 15;
    const size_t base  = (size_t)b * S * D + (size_t)h * DH;
    const size_t vbase = (size_t)bh * DH * S;
    const int qtt[2] = {pj, 31 - pj};          // tile A (short), tile B (long)
    const int nchunk = (33 - pj) >> 1;         // ceil((32-pj)/2); staging stays <= row 2047

    // stage one 128-key chunk (both halves) into buffer `buf`
    auto STAGE = [&](int buf, int kn) {
#pragma unroll
        for (int hh = 0; hh < 2; hh++)
#pragma unroll
            for (int j = 0; j < 2; j++) {
                const int s = wave * 128 + j * 64 + lane;
                const int r = s >> 3, c = (s ^ r) & 7;
                gload_lds16(K  + base  + (size_t)(kn + hh * 64 + r) * D + c * 8,
                            &Ks[buf][hh][(wave * 128 + j * 64) * 8]);
                gload_lds16(Vg + vbase + (size_t)r * S + kn + hh * 64 + c * 8,
                            &Vt[buf][hh][(wave * 128 + j * 64) * 8]);
            }
    };

    // ---- prologue: stage chunk 0; Q B-frags for BOTH tiles direct from global
    STAGE(0, 0);
    frag_ab qf[2][2];
#pragma unroll
    for (int t = 0; t < 2; t++) {
        const bf16* qp = Q + base + (size_t)(qtt[t] * 64 + wave * 16 + r16) * D + quad * 8;
#pragma unroll
        for (int ks = 0; ks < 2; ks++)
            qf[t][ks] = *(const frag_ab*)(qp + ks * 32);
    }
    __syncthreads();   // chunk 0 resident

    // all-ones bf16 A-fragment for the l-sum MFMA (1.0 = 0x3F80)
    const frag_ab onesf = {(short)0x3F80, (short)0x3F80, (short)0x3F80, (short)0x3F80,
                           (short)0x3F80, (short)0x3F80, (short)0x3F80, (short)0x3F80};

    frag_cd Oacc[2][4];   // per tile: O^T row=d(quad*4+rg), col=q(r16)
    frag_cd Lacc[2];
#pragma unroll
    for (int t = 0; t < 2; t++) {
        Lacc[t] = frag_cd{0.f, 0.f, 0.f, 0.f};
#pragma unroll
        for (int nd = 0; nd < 4; nd++) Oacc[t][nd] = frag_cd{0.f, 0.f, 0.f, 0.f};
    }

    const int qrow = wave * 16 + r16;

    for (int chunk = 0; chunk < nchunk; chunk++) {
        const int cur = chunk & 1;
        if (chunk + 1 < nchunk) STAGE(cur ^ 1, (chunk + 1) * 128);

#pragma unroll
        for (int hh = 0; hh < 2; hh++) {
            const int k64 = chunk * 2 + hh;     // 64-key tile index (uniform)
            if (k64 <= qtt[1]) {                // skip overshoot half (uniform branch)
                // ---- ka/vb: shared by both q-tiles (R14 layouts verbatim)
                frag_ab ka[4][2], vb[4][2];
#pragma unroll
                for (int mk = 0; mk < 4; mk++) {
                    const int row = mk * 16 + r16;
#pragma unroll
                    for (int ks = 0; ks < 2; ks++)
                        ka[mk][ks] = *(const frag_ab*)
                            &Ks[cur][hh][row * 64 + (((ks * 4 + quad) ^ (row & 7)) * 8)];
                }
#pragma unroll
                for (int nd = 0; nd < 4; nd++) {
                    const int row = nd * 16 + r16;
#pragma unroll
                    for (int ks = 0; ks < 2; ks++)
                        vb[nd][ks] = *(const frag_ab*)
                            &Vt[cur][hh][row * 64 + (((ks * 4 + quad) ^ (row & 7)) * 8)];
                }

#pragma unroll
                for (int t = 0; t < 2; t++) {
                    if (k64 <= qtt[t]) {        // tile active? (uniform)
                        const int q0t = qtt[t] * 64;
                        // QK^T: S^T col(r16)=q, row(quad*4+rg in mk-tile)=key
                        frag_cd Sc[4];
#pragma unroll
                        for (int mk = 0; mk < 4; mk++) {
                            Sc[mk] = frag_cd{0.f, 0.f, 0.f, 0.f};
#pragma unroll
                            for (int ks = 0; ks < 2; ks++)
                                Sc[mk] = __builtin_amdgcn_mfma_f32_16x16x32_bf16(
                                    ka[mk][ks], qf[t][ks], Sc[mk], 0, 0, 0);
                        }
                        // static-max softmax: P = exp2(s) (log2-domain, KSCALE in Q)
                        const bool domask = (k64 == qtt[t]);   // only diagonal straddles
                        const int qg = q0t + qrow;
#pragma unroll
                        for (int mk = 0; mk < 4; mk++) {
                            __align__(8) bf16 t4[4];
#pragma unroll
                            for (int rg = 0; rg < 4; rg++) {
                                float sv = Sc[mk][rg];
                                if (domask) {
                                    const int keyg = k64 * 64 + mk * 16 + quad * 4 + rg;
                                    sv = (keyg <= qg) ? sv : -1e30f;
                                }
                                t4[rg] = __float2bfloat16(__builtin_amdgcn_exp2f(sv));
                            }
                            const int g2 = (mk * 4 + quad) ^ r16;
                            *(ull*)&Ps[qrow * 64 + g2 * 4] = *(const ull*)t4;
                        }
                        // no barrier: Ps rows wave-private; per-wave LDS ops in-order
                        frag_ab pa[2];
#pragma unroll
                        for (int ks = 0; ks < 2; ks++) {
                            const int gb = ks * 8 + quad * 2;
                            union { ull u[2]; frag_ab f; } tp;
                            tp.u[0] = *(const ull*)&Ps[qrow * 64 + ((gb    ) ^ r16) * 4];
                            tp.u[1] = *(const ull*)&Ps[qrow * 64 + ((gb + 1) ^ r16) * 4];
                            pa[ks] = tp.f;
                        }
#pragma unroll
                        for (int nd = 0; nd < 4; nd++)
#pragma unroll
                            for (int ks = 0; ks < 2; ks++)
                                Oacc[t][nd] = __builtin_amdgcn_mfma_f32_16x16x32_bf16(
                                    vb[nd][ks], pa[ks], Oacc[t][nd], 0, 0, 0);
#pragma unroll
                        for (int ks = 0; ks < 2; ks++)
                            Lacc[t] = __builtin_amdgcn_mfma_f32_16x16x32_bf16(
                                onesf, pa[ks], Lacc[t], 0, 0, 0);
                    }
                }
            }
        }

        __syncthreads();   // joins: prefetch complete + all waves done with cur bufs
    }

    // ---- epilogue: both tiles — Ctx[q][d] = O^T[d][q] / l (l in Lacc[t][0])
#pragma unroll
    for (int t = 0; t < 2; t++) {
        const float invl = 1.f / Lacc[t][0];
        const int qg = qtt[t] * 64 + qrow;
#pragma unroll
        for (int nd = 0; nd < 4; nd++) {
            __align__(8) bf16 t4[4];
#pragma unroll
            for (int rg = 0; rg < 4; rg++)
                t4[rg] = __float2bfloat16(Oacc[t][nd][rg] * invl);
            *(ull*)(Ctx + base + (size_t)qg * D + nd * 16 + quad * 4) = *(const ull*)t4;
        }
    }
}

// ---------- output projection, 64x128 tiles, single-barrier dbuf K-loop
__global__ __launch_bounds__(256) void gemm_out64(const bf16* __restrict__ A, const bf16* __restrict__ Bt,
                                                  const float* __restrict__ bias, float* __restrict__ Out) {
    __shared__ __align__(16) bf16 As[2][64 * BK];
    __shared__ __align__(16) bf16 Bs[2][128 * BK];
    const int tid = threadIdx.x, wave = tid >> 6, lane = tid & 63;
    const int r16 = lane & 15, quad = lane >> 4;
    const int row0 = blockIdx.y * 64;
    const int col0 = blockIdx.x * 128;
    const int wm = (wave & 1) * 32, wn = (wave >> 1) * 64;

    frag_cd acc[2][4];
#pragma unroll
    for (int mt = 0; mt < 2; mt++)
#pragma unroll
        for (int nt = 0; nt < 4; nt++) acc[mt][nt] = frag_cd{0.f, 0.f, 0.f, 0.f};

#pragma unroll
    for (int j = 0; j < 2; j++) {
        const int s = wave * 128 + j * 64 + lane;
        const int r = s >> 3, c = (s ^ r) & 7;
        gload_lds16(A + (size_t)(row0 + r) * D + c * 8, &As[0][(wave * 128 + j * 64) * 8]);
    }
#pragma unroll
    for (int j = 0; j < 4; j++) {
        const int s = wave * 256 + j * 64 + lane;
        const int r = s >> 3, c = (s ^ r) & 7;
        gload_lds16(Bt + (size_t)(col0 + r) * D + c * 8, &Bs[0][(wave * 256 + j * 64) * 8]);
    }
    __syncthreads();

    for (int kt = 0; kt < D / BK; kt++) {
        const int cur = kt & 1;
        if (kt + 1 < D / BK) {
            const int kn = (kt + 1) * BK;
#pragma unroll
            for (int j = 0; j < 2; j++) {
                const int s = wave * 128 + j * 64 + lane;
                const int r = s >> 3, c = (s ^ r) & 7;
                gload_lds16(A + (size_t)(row0 + r) * D + kn + c * 8,
                            &As[cur ^ 1][(wave * 128 + j * 64) * 8]);
            }
#pragma unroll
            for (int j = 0; j < 4; j++) {
                const int s = wave * 256 + j * 64 + lane;
                const int r = s >> 3, c = (s ^ r) & 7;
                gload_lds16(Bt + (size_t)(col0 + r) * D + kn + c * 8,
                            &Bs[cur ^ 1][(wave * 256 + j * 64) * 8]);
            }
        }

        frag_ab af[2][2], bf[4][2];
#pragma unroll
        for (int mt = 0; mt < 2; mt++) {
            const int row = wm + mt * 16 + r16;
#pragma unroll
            for (int ks = 0; ks < 2; ks++)
                af[mt][ks] = *(const frag_ab*)&As[cur][row * 64 + (((ks * 4 + quad) ^ (row & 7)) * 8)];
        }
#pragma unroll
        for (int nt = 0; nt < 4; nt++) {
            const int row = wn + nt * 16 + r16;
#pragma unroll
            for (int ks = 0; ks < 2; ks++)
                bf[nt][ks] = *(const frag_ab*)&Bs[cur][row * 64 + (((ks * 4 + quad) ^ (row & 7)) * 8)];
        }
#pragma unroll
        for (int mt = 0; mt < 2; mt++)
#pragma unroll
            for (int nt = 0; nt < 4; nt++)
#pragma unroll
                for (int ks = 0; ks < 2; ks++)
                    acc[mt][nt] = __builtin_amdgcn_mfma_f32_16x16x32_bf16(
                        af[mt][ks], bf[nt][ks], acc[mt][nt], 0, 0, 0);

        __syncthreads();
    }

#pragma unroll
    for (int mt = 0; mt < 2; mt++)
#pragma unroll
        for (int nt = 0; nt < 4; nt++) {
            const int col = col0 + wn + nt * 16 + r16;
            const float bv = bias[col];
#pragma unroll
            for (int rg = 0; rg < 4; rg++) {
                const int row = row0 + wm + mt * 16 + quad * 4 + rg;
                Out[(size_t)row * D + col] = acc[mt][nt][rg] + bv;
            }
        }
}

extern "C" void kernel_launch(void* const* d_in, const int* in_sizes, int n_in,
                              void* d_out, int out_size, void* d_ws, size_t ws_size,
                              hipStream_t stream) {
    const float* x  = (const float*)d_in[0];
    const float* Wq = (const float*)d_in[1];
    const float* Wk = (const float*)d_in[2];
    const float* Wv = (const float*)d_in[3];
    const float* Wo = (const float*)d_in[4];
    const float* bo = (const float*)d_in[5];
    float* out = (float*)d_out;

    bf16* xb    = (bf16*)d_ws;                 // [4096][1024]
    bf16* WqkvT = xb    + (size_t)M * D;       // [3072][1024] (WqT|WkT|WvT)
    bf16* WoT   = WqkvT + (size_t)3 * D * D;   // [1024][1024]
    bf16* Qb    = WoT   + (size_t)D * D;       // [B,S,D] (pre-scaled by KSCALE)
    bf16* Kb    = Qb    + (size_t)M * D;       // [B,S,D]
    bf16* Vt_g  = Kb    + (size_t)M * D;       // [32][64][2048]
    bf16* Ctxb  = Vt_g  + (size_t)M * D;       // [B,S,D]

    prep<<<dim3(32, 32, 5), 256, 0, stream>>>(x, xb, Wq, Wk, Wv, Wo,
                                              WqkvT, WqkvT + (size_t)D * D,
                                              WqkvT + (size_t)2 * D * D, WoT);
    gemm_qkv_all<<<dim3(24, 32), 256, 0, stream>>>(xb, WqkvT, Qb, Kb, Vt_g);
    attn_mfma<<<dim3(B * NH, 16), 256, 0, stream>>>(Qb, Kb, Vt_g, Ctxb);
    gemm_out64<<<dim3(8, 64), 256, 0, stream>>>(Ctxb, WoT, bo, out);
}